// Round 16
// baseline (79.656 us; speedup 1.0000x reference)
//
#include <hip/hip_runtime.h>
#include <hip/hip_fp16.h>
#include <cstdint>

#define BB 2
#define SS 512
#define EE 256
#define NN (BB*SS)           // 1024 rows
#define KTOT (EE*EE)         // 65536
#define SPLITK 32
#define KCHUNK (KTOT/SPLITK) // 2048
#define NSTEP 32             // BK=64 steps per chunk
#define TSTEPS (KTOT/32)     // 2048 packed 32-k blocks
#define LN_EPS 1e-3f

typedef _Float16 f16;
typedef _Float16 f16x8 __attribute__((ext_vector_type(8)));
typedef float    f32x4 __attribute__((ext_vector_type(4)));

#define NPACK 512            // pack blocks: 4 cgroups x 128 kgroups

// ---------------- Kernel 1: FUSED pack (LDS transpose) + wprefix.
__global__ void prep_kernel(const float* __restrict__ cm, f16* __restrict__ cmP,
                            const float* __restrict__ x, float* __restrict__ ps) {
    __shared__ __align__(16) char smem[35072];
    const int bid = blockIdx.x;
    const int tid = threadIdx.x;
    const int wave = tid >> 6;
    const int lane = tid & 63;

    if (bid < NPACK) {
        const int cg = bid >> 7;          // 0..3
        const int kg = bid & 127;         // 0..127
        f16* lt = (f16*)smem;             // [64 slots][264] (pad 8)
        #pragma unroll
        for (int h = 0; h < 2; ++h) {
            #pragma unroll
            for (int i = 0; i < 8; ++i) {
                const int rl = i * 4 + wave;                   // 0..31
                const int row = cg * 64 + h * 32 + rl;
                const float* src = cm + (size_t)row * KTOT + kg * 512 + lane * 8;
                float4 lo = *(const float4*)(src);
                float4 hi = *(const float4*)(src + 4);
                f16x8 v = { (f16)lo.x, (f16)lo.y, (f16)lo.z, (f16)lo.w,
                            (f16)hi.x, (f16)hi.y, (f16)hi.z, (f16)hi.w };
                *(f16x8*)(lt + lane * 264 + rl * 8) = v;
            }
            __syncthreads();
            #pragma unroll
            for (int jj = 0; jj < 8; ++jj) {
                const int s  = jj * 8 + wave * 2 + (lane >> 5);  // slot 0..63
                const int cl = lane & 31;
                f16x8 v = *(const f16x8*)(lt + s * 264 + cl * 8);
                const int t    = kg * 16 + (s >> 2);
                const int koct = s & 3;
                const int c    = cg * 64 + h * 32 + cl;
                *(f16x8*)(cmP + (size_t)t * 8192 + koct * 2048 + c * 8) = v;
            }
            __syncthreads();
        }
        return;
    }

    // ---- wprefix
    float (*xt)[128] = (float(*)[128])smem;            // 64 x 128 f32
    float* wl2 = (float*)(smem + 32768);               // 576 f32
    const int id = bid - NPACK;            // 0..143
    const int eh = id & 1;
    const int rest = id >> 1;
    const int b = rest / 36;
    const int r = rest % 36;
    int it = 0;
    while ((it + 1) * (it + 2) / 2 <= r) ++it;
    const int jt = r - it * (it + 1) / 2;

    for (int t = tid; t < 576; t += 256) {
        const int d = t - 64;
        wl2[t] = (d > 0) ? 1.0f / ((float)d * (float)d) : 0.0f;
    }
    const int jbase = jt * 64, ibase = it * 64;
    const float* xb = x + ((size_t)b * SS + jbase) * EE + eh * 128;
    #pragma unroll
    for (int p = 0; p < 8; ++p) {
        const int row = p * 8 + (tid >> 5);
        const int col = (tid & 31) * 4;
        *(float4*)&xt[row][col] = *(const float4*)(xb + (size_t)row * EE + col);
    }
    __syncthreads();

    const int g  = tid >> 5;
    const int ec = (tid & 31) * 4;
    const int irow = ibase + g * 8;
    float4 acc[8];
    #pragma unroll
    for (int m = 0; m < 8; ++m) acc[m] = (float4){0.f, 0.f, 0.f, 0.f};

    for (int jj = 0; jj < 64; ++jj) {
        const float4 xv = *(const float4*)&xt[jj][ec];
        const int wbase = irow - (jbase + jj) + 64;
        #pragma unroll
        for (int m = 0; m < 8; ++m) {
            const float w = wl2[wbase + m];
            acc[m].x += xv.x * w;
            acc[m].y += xv.y * w;
            acc[m].z += xv.z * w;
            acc[m].w += xv.w * w;
        }
    }

    float* base = ps + ((size_t)(((b * 2 + eh) * 8 + it) * 8 + jt)) * (64 * 128);
    #pragma unroll
    for (int m = 0; m < 8; ++m)
        *(float4*)(base + (size_t)(g * 8 + m) * 128 + ec) = acc[m];
}

// ---------------- Kernel 1b: fold j-tile partials -> s[n,e]
__global__ void reduce_s_kernel(const float* __restrict__ ps, float* __restrict__ s) {
    const int n = blockIdx.x;
    const int e = threadIdx.x;
    const int b = n >> 9, i = n & (SS - 1);
    const int it = i >> 6, il = i & 63;
    const int eh = e >> 7, ec = e & 127;
    const size_t tbase = (size_t)((b * 2 + eh) * 8 + it) * 8;
    float acc = 0.0f;
    for (int jt = 0; jt <= it; ++jt)
        acc += ps[(tbase + jt) * (64 * 128) + (size_t)il * 128 + ec];
    s[(size_t)n * EE + e] = acc;
}

// ---------------- Kernel 2: split-K MFMA GEMM — BK=64 merged steps:
// 32 steps, each = one vmcnt drain + one 8-load stage + 2 x {4 ds_read ->
// af -> 16 MFMA}. 2 LDS bufs x 32 KB, barrier-free (stage==read-set),
// f16 LDS-staged epilogue.
__launch_bounds__(256, 2)
__global__ void gemm_kernel(const float* __restrict__ x,
                            const float* __restrict__ sbuf,
                            const f16* __restrict__ cmP,
                            f16* __restrict__ part) {
    __shared__ __align__(16) f16 Bs[2][16384];   // 2 x 32 KB
    const int tid  = threadIdx.x;
    const int lane = tid & 63;
    const int wave = tid >> 6;       // col-quarter 0..3
    const int koct = lane >> 4;      // k-octet 0..3
    const int cl   = lane & 15;

    const int d = blockIdx.x;            // 0..511
    const int nblock = (d >> 3) & 15;
    const int chunk  = (d & 7) * 4 + (d >> 7);   // XCD-grouped chunks

    // ---- xf loads (8 global loads)
    f16x8 xf[4];
    #pragma unroll
    for (int rt = 0; rt < 4; ++rt) {
        const int r = nblock * 64 + rt * 16 + cl;
        const float* xr = x + (size_t)r * EE + chunk * 8;
        float4 xlo = *(const float4*)(xr);
        float4 xhi = *(const float4*)(xr + 4);
        xf[rt] = (f16x8){ (f16)xlo.x, (f16)xlo.y, (f16)xlo.z, (f16)xlo.w,
                          (f16)xhi.x, (f16)xhi.y, (f16)xhi.z, (f16)xhi.w };
    }
    // ---- svm m=0 loads (8 global loads)
    float4 p0[4][2];
    #pragma unroll
    for (int rt = 0; rt < 4; ++rt) {
        const int r = nblock * 64 + rt * 16 + cl;
        const float* sr = sbuf + (size_t)r * EE + koct * 8;
        p0[rt][0] = *(const float4*)(sr);
        p0[rt][1] = *(const float4*)(sr + 4);
    }
    __builtin_amdgcn_sched_barrier(0);

    f32x4 acc[4][4];
    #pragma unroll
    for (int a = 0; a < 4; ++a)
        #pragma unroll
        for (int b = 0; b < 4; ++b) acc[a][b] = (f32x4){0.f, 0.f, 0.f, 0.f};

    // chunk covers 64 packed 32-k blocks
    const char* srcBase = (const char*)cmP + (size_t)chunk * 64 * 16384;
    // step v (0..31): ap = v&3, m = v>>2; t0 = 16*ap + m, t1 = t0 + 8.
    // Wave stages its read-set for both t-blocks: 8 x 16B/lane.
    auto stageV = [&](int v) {
        const int t0 = 16 * (v & 3) + (v >> 2);
        const char* g = srcBase + (size_t)t0 * 16384 + wave * 1024 + lane * 16;
        char* l = (char*)&Bs[v & 1][0] + wave * 1024;
        #pragma unroll
        for (int tt = 0; tt < 2; ++tt)
            #pragma unroll
            for (int i = 0; i < 4; ++i) {
                __builtin_amdgcn_global_load_lds(
                    (const __attribute__((address_space(1))) void*)(g + tt * 131072 + i * 4096),
                    (__attribute__((address_space(3))) void*)(l + tt * 16384 + i * 4096),
                    16, 0, 0);
            }
    };

    stageV(0);
    asm volatile("s_waitcnt vmcnt(0)" ::: "memory");   // xf, svm, stage(0) done
    __builtin_amdgcn_sched_barrier(0);

    f16x8 svm[4];
    #pragma unroll
    for (int rt = 0; rt < 4; ++rt)
        svm[rt] = (f16x8){ (f16)p0[rt][0].x, (f16)p0[rt][0].y,
                           (f16)p0[rt][0].z, (f16)p0[rt][0].w,
                           (f16)p0[rt][1].x, (f16)p0[rt][1].y,
                           (f16)p0[rt][1].z, (f16)p0[rt][1].w };

    const int cb = koct * 2048 + (wave * 64 + cl) * 8;

    #pragma unroll
    for (int m = 0; m < 8; ++m) {
        float4 pnxt[4][2];
        #pragma unroll
        for (int ap = 0; ap < 4; ++ap) {
            const int v = m * 4 + ap;

            if (v > 0) {
                asm volatile("s_waitcnt vmcnt(0)" ::: "memory");  // stage(v)+svm done
                __builtin_amdgcn_sched_barrier(0);
            }
            if (ap == 0 && m > 0) {   // new m's svm (drained above)
                #pragma unroll
                for (int rt = 0; rt < 4; ++rt)
                    svm[rt] = (f16x8){ (f16)pnxt[rt][0].x, (f16)pnxt[rt][0].y,
                                       (f16)pnxt[rt][0].z, (f16)pnxt[rt][0].w,
                                       (f16)pnxt[rt][1].x, (f16)pnxt[rt][1].y,
                                       (f16)pnxt[rt][1].z, (f16)pnxt[rt][1].w };
            }

            const f16* bbase = &Bs[v & 1][0];

            // ---- half-step A (t0, a = 2*ap)
            f16x8 bf[4];
            #pragma unroll
            for (int ct = 0; ct < 4; ++ct)
                bf[ct] = *(const f16x8*)(bbase + cb + ct * 128);

            if (v + 1 < NSTEP) stageV(v + 1);   // issue early: full-step slack

            f16x8 af[4];
            #pragma unroll
            for (int rt = 0; rt < 4; ++rt) {
                const f16 xa = xf[rt][2 * ap];
                const f16x8 xa8 = { xa, xa, xa, xa, xa, xa, xa, xa };
                af[rt] = xa8 * svm[rt];
            }
            __builtin_amdgcn_s_setprio(1);
            #pragma unroll
            for (int ct = 0; ct < 4; ++ct)
                #pragma unroll
                for (int rt = 0; rt < 4; ++rt)
                    acc[rt][ct] = __builtin_amdgcn_mfma_f32_16x16x32_f16(af[rt], bf[ct], acc[rt][ct], 0, 0, 0);
            __builtin_amdgcn_s_setprio(0);

            // ---- half-step B (t1, a = 2*ap+1)
            #pragma unroll
            for (int ct = 0; ct < 4; ++ct)
                bf[ct] = *(const f16x8*)(bbase + 8192 + cb + ct * 128);
            #pragma unroll
            for (int rt = 0; rt < 4; ++rt) {
                const f16 xa = xf[rt][2 * ap + 1];
                const f16x8 xa8 = { xa, xa, xa, xa, xa, xa, xa, xa };
                af[rt] = xa8 * svm[rt];
            }
            __builtin_amdgcn_s_setprio(1);
            #pragma unroll
            for (int ct = 0; ct < 4; ++ct)
                #pragma unroll
                for (int rt = 0; rt < 4; ++rt)
                    acc[rt][ct] = __builtin_amdgcn_mfma_f32_16x16x32_f16(af[rt], bf[ct], acc[rt][ct], 0, 0, 0);
            __builtin_amdgcn_s_setprio(0);

            // next-m svm loads, 2 steps of slack
            if (ap == 2 && m < 7) {
                #pragma unroll
                for (int rt = 0; rt < 4; ++rt) {
                    const int r = nblock * 64 + rt * 16 + cl;
                    const float* sr = sbuf + (size_t)r * EE + (m + 1) * 32 + koct * 8;
                    pnxt[rt][0] = *(const float4*)(sr);
                    pnxt[rt][1] = *(const float4*)(sr + 4);
                }
                __builtin_amdgcn_sched_barrier(0);
            }
        }
    }

    // ---- Epilogue: f16 via padded LDS stage, then contiguous row stores.
    __syncthreads();                      // rendezvous drifted waves; Bs free
    f16* Ep = (f16*)&Bs[0][0];            // [64][264] padded, 33.8 KB
    #pragma unroll
    for (int rt = 0; rt < 4; ++rt) {
        #pragma unroll
        for (int ct = 0; ct < 4; ++ct) {
            const int col = wave * 64 + ct * 16 + cl;
            #pragma unroll
            for (int q = 0; q < 4; ++q) {
                const int lr = rt * 16 + koct * 4 + q;
                Ep[lr * 264 + col] = (f16)acc[rt][ct][q];
            }
        }
    }
    __syncthreads();
    {
        const int lr  = tid >> 2;         // 0..63
        const int seg = tid & 3;          // 0..3 (64 cols each)
        f16* dst = part + ((size_t)chunk * NN + nblock * 64 + lr) * EE + seg * 64;
        const f16* srcE = Ep + lr * 264 + seg * 64;
        #pragma unroll
        for (int i = 0; i < 8; ++i)
            *(f16x8*)(dst + i * 8) = *(const f16x8*)(srcE + i * 8);
    }
}

// ---------------- Kernel 3: split-K reduce + residual + LayerNorm (f16 partials)
__global__ void reduce_ln_kernel(const float* __restrict__ x,
                                 const f16* __restrict__ part,
                                 const float* __restrict__ gamma,
                                 const float* __restrict__ beta,
                                 float* __restrict__ out) {
    const int n = blockIdx.x;
    const int c = threadIdx.x;
    const int lane = c & 63, wave = c >> 6;
    float y = x[(size_t)n * EE + c];
    #pragma unroll 8
    for (int ch = 0; ch < SPLITK; ++ch)
        y += (float)part[((size_t)ch * NN + n) * EE + c];

    float v = y;
    #pragma unroll
    for (int o = 32; o > 0; o >>= 1) v += __shfl_xor(v, o);
    __shared__ float red[8];
    if (lane == 0) red[wave] = v;
    __syncthreads();
    const float mean = (red[0] + red[1] + red[2] + red[3]) * (1.0f / EE);
    const float d = y - mean;
    float sq = d * d;
    #pragma unroll
    for (int o = 32; o > 0; o >>= 1) sq += __shfl_xor(sq, o);
    if (lane == 0) red[4 + wave] = sq;
    __syncthreads();
    const float var = (red[4] + red[5] + red[6] + red[7]) * (1.0f / EE);
    out[(size_t)n * EE + c] = d * rsqrtf(var + LN_EPS) * gamma[c] + beta[c];
}

extern "C" void kernel_launch(void* const* d_in, const int* in_sizes, int n_in,
                              void* d_out, int out_size, void* d_ws, size_t ws_size,
                              hipStream_t stream) {
    const float* x     = (const float*)d_in[0];
    const float* cm    = (const float*)d_in[1];
    const float* gamma = (const float*)d_in[2];
    const float* beta  = (const float*)d_in[3];
    float* out = (float*)d_out;

    float* sbuf = (float*)d_ws;                                    // 1 MB
    f16*   cmP  = (f16*)(sbuf + (size_t)NN * EE);                  // 33.5 MB
    f16*   part = (f16*)((char*)cmP + (size_t)TSTEPS * 8192 * sizeof(f16)); // 16.8 MB
    float* ps   = (float*)part;  // prefix partials (8.4 MB) alias part —
                                 // consumed by reduce_s before gemm writes part.

    hipLaunchKernelGGL(prep_kernel, dim3(NPACK + 144), dim3(256), 0, stream,
                       cm, cmP, x, ps);
    hipLaunchKernelGGL(reduce_s_kernel, dim3(NN), dim3(256), 0, stream, ps, sbuf);
    hipLaunchKernelGGL(gemm_kernel, dim3(16 * SPLITK), dim3(256), 0, stream,
                       x, sbuf, cmP, part);
    hipLaunchKernelGGL(reduce_ln_kernel, dim3(NN), dim3(256), 0, stream,
                       x, part, gamma, beta, out);
}

// Round 17
// 72.340 us; speedup vs baseline: 1.1011x; 1.1011x over previous
//
#include <hip/hip_runtime.h>
#include <hip/hip_fp16.h>
#include <cstdint>

#define BB 2
#define SS 512
#define EE 256
#define NN (BB*SS)           // 1024 rows
#define KTOT (EE*EE)         // 65536
#define SPLITK 32
#define KCHUNK (KTOT/SPLITK) // 2048
#define NSTEP (KCHUNK/32)    // 64 k-steps per chunk
#define TSTEPS (KTOT/32)     // 2048 packed 32-k blocks
#define LN_EPS 1e-3f

typedef _Float16 f16;
typedef _Float16 f16x8 __attribute__((ext_vector_type(8)));
typedef float    f32x4 __attribute__((ext_vector_type(4)));

#define NPACK 512            // pack blocks: 4 cgroups x 128 kgroups

// ---------------- Kernel 1: FUSED pack (LDS transpose) + wprefix.
__global__ void prep_kernel(const float* __restrict__ cm, f16* __restrict__ cmP,
                            const float* __restrict__ x, float* __restrict__ ps) {
    __shared__ __align__(16) char smem[35072];
    const int bid = blockIdx.x;
    const int tid = threadIdx.x;
    const int wave = tid >> 6;
    const int lane = tid & 63;

    if (bid < NPACK) {
        const int cg = bid >> 7;          // 0..3
        const int kg = bid & 127;         // 0..127
        f16* lt = (f16*)smem;             // [64 slots][264] (pad 8)
        #pragma unroll
        for (int h = 0; h < 2; ++h) {
            #pragma unroll
            for (int i = 0; i < 8; ++i) {
                const int rl = i * 4 + wave;                   // 0..31
                const int row = cg * 64 + h * 32 + rl;
                const float* src = cm + (size_t)row * KTOT + kg * 512 + lane * 8;
                float4 lo = *(const float4*)(src);
                float4 hi = *(const float4*)(src + 4);
                f16x8 v = { (f16)lo.x, (f16)lo.y, (f16)lo.z, (f16)lo.w,
                            (f16)hi.x, (f16)hi.y, (f16)hi.z, (f16)hi.w };
                *(f16x8*)(lt + lane * 264 + rl * 8) = v;
            }
            __syncthreads();
            #pragma unroll
            for (int jj = 0; jj < 8; ++jj) {
                const int s  = jj * 8 + wave * 2 + (lane >> 5);  // slot 0..63
                const int cl = lane & 31;
                f16x8 v = *(const f16x8*)(lt + s * 264 + cl * 8);
                const int t    = kg * 16 + (s >> 2);
                const int koct = s & 3;
                const int c    = cg * 64 + h * 32 + cl;
                *(f16x8*)(cmP + (size_t)t * 8192 + koct * 2048 + c * 8) = v;
            }
            __syncthreads();
        }
        return;
    }

    // ---- wprefix
    float (*xt)[128] = (float(*)[128])smem;            // 64 x 128 f32
    float* wl2 = (float*)(smem + 32768);               // 576 f32
    const int id = bid - NPACK;            // 0..143
    const int eh = id & 1;
    const int rest = id >> 1;
    const int b = rest / 36;
    const int r = rest % 36;
    int it = 0;
    while ((it + 1) * (it + 2) / 2 <= r) ++it;
    const int jt = r - it * (it + 1) / 2;

    for (int t = tid; t < 576; t += 256) {
        const int d = t - 64;
        wl2[t] = (d > 0) ? 1.0f / ((float)d * (float)d) : 0.0f;
    }
    const int jbase = jt * 64, ibase = it * 64;
    const float* xb = x + ((size_t)b * SS + jbase) * EE + eh * 128;
    #pragma unroll
    for (int p = 0; p < 8; ++p) {
        const int row = p * 8 + (tid >> 5);
        const int col = (tid & 31) * 4;
        *(float4*)&xt[row][col] = *(const float4*)(xb + (size_t)row * EE + col);
    }
    __syncthreads();

    const int g  = tid >> 5;
    const int ec = (tid & 31) * 4;
    const int irow = ibase + g * 8;
    float4 acc[8];
    #pragma unroll
    for (int m = 0; m < 8; ++m) acc[m] = (float4){0.f, 0.f, 0.f, 0.f};

    for (int jj = 0; jj < 64; ++jj) {
        const float4 xv = *(const float4*)&xt[jj][ec];
        const int wbase = irow - (jbase + jj) + 64;
        #pragma unroll
        for (int m = 0; m < 8; ++m) {
            const float w = wl2[wbase + m];
            acc[m].x += xv.x * w;
            acc[m].y += xv.y * w;
            acc[m].z += xv.z * w;
            acc[m].w += xv.w * w;
        }
    }

    float* base = ps + ((size_t)(((b * 2 + eh) * 8 + it) * 8 + jt)) * (64 * 128);
    #pragma unroll
    for (int m = 0; m < 8; ++m)
        *(float4*)(base + (size_t)(g * 8 + m) * 128 + ec) = acc[m];
}

// ---------------- Kernel 1b: fold j-tile partials -> s[n,e]
__global__ void reduce_s_kernel(const float* __restrict__ ps, float* __restrict__ s) {
    const int n = blockIdx.x;
    const int e = threadIdx.x;
    const int b = n >> 9, i = n & (SS - 1);
    const int it = i >> 6, il = i & 63;
    const int eh = e >> 7, ec = e & 127;
    const size_t tbase = (size_t)((b * 2 + eh) * 8 + it) * 8;
    float acc = 0.0f;
    for (int jt = 0; jt <= it; ++jt)
        acc += ps[(tbase + jt) * (64 * 128) + (size_t)il * 128 + ec];
    s[(size_t)n * EE + e] = acc;
}

// ---------------- Kernel 2: split-K MFMA GEMM — B loaded DIRECTLY into
// registers (no LDS in main loop; LDS was a pure pass-through since the
// stage-set == read-set). 4 rotating reg buffers, loads 3 steps ahead,
// compiler-inserted counted vmcnt handles all waits. LDS = epilogue only.
__launch_bounds__(256, 2)
__global__ void gemm_kernel(const float* __restrict__ x,
                            const float* __restrict__ sbuf,
                            const f16* __restrict__ cmP,
                            f16* __restrict__ part) {
    __shared__ __align__(16) f16 Ep[64 * 264];   // epilogue stage, 33.8 KB
    const int tid  = threadIdx.x;
    const int lane = tid & 63;
    const int wave = tid >> 6;       // col-quarter 0..3
    const int koct = lane >> 4;      // k-octet 0..3
    const int cl   = lane & 15;

    const int d = blockIdx.x;            // 0..511
    const int nblock = (d >> 3) & 15;
    const int chunk  = (d & 7) * 4 + (d >> 7);   // XCD-grouped chunks

    // ---- xf loads (8 global loads)
    f16x8 xf[4];
    #pragma unroll
    for (int rt = 0; rt < 4; ++rt) {
        const int r = nblock * 64 + rt * 16 + cl;
        const float* xr = x + (size_t)r * EE + chunk * 8;
        float4 xlo = *(const float4*)(xr);
        float4 xhi = *(const float4*)(xr + 4);
        xf[rt] = (f16x8){ (f16)xlo.x, (f16)xlo.y, (f16)xlo.z, (f16)xlo.w,
                          (f16)xhi.x, (f16)xhi.y, (f16)xhi.z, (f16)xhi.w };
    }
    // ---- svm m=0 loads (8 global loads)
    float4 p0[4][2];
    #pragma unroll
    for (int rt = 0; rt < 4; ++rt) {
        const int r = nblock * 64 + rt * 16 + cl;
        const float* sr = sbuf + (size_t)r * EE + koct * 8;
        p0[rt][0] = *(const float4*)(sr);
        p0[rt][1] = *(const float4*)(sr + 4);
    }

    // per-lane B base: chunk slice + koct slot + wave slice + col-low
    const char* bbase = (const char*)cmP + (size_t)chunk * (64 * 16384)
                      + koct * 4096 + wave * 1024 + cl * 16;
    // step v covers packed block t = ((v&7)<<3)|(v>>3)
    #define TOFF(v) ((size_t)((((v) & 7) << 3) | ((v) >> 3)) * 16384)
    #define LOADB(BUF, v) do {                                              \
        _Pragma("unroll")                                                   \
        for (int ct_ = 0; ct_ < 4; ++ct_)                                   \
            BUF[ct_] = *(const f16x8*)(bbase + TOFF(v) + ct_ * 256);        \
    } while (0)

    f16x8 b0[4], b1[4], b2[4], b3[4];
    LOADB(b0, 0); LOADB(b1, 1); LOADB(b2, 2);
    __builtin_amdgcn_sched_barrier(0);

    f32x4 acc[4][4];
    #pragma unroll
    for (int a = 0; a < 4; ++a)
        #pragma unroll
        for (int b = 0; b < 4; ++b) acc[a][b] = (f32x4){0.f, 0.f, 0.f, 0.f};

    f16x8 svm[4];
    #pragma unroll
    for (int rt = 0; rt < 4; ++rt)
        svm[rt] = (f16x8){ (f16)p0[rt][0].x, (f16)p0[rt][0].y,
                           (f16)p0[rt][0].z, (f16)p0[rt][0].w,
                           (f16)p0[rt][1].x, (f16)p0[rt][1].y,
                           (f16)p0[rt][1].z, (f16)p0[rt][1].w };

    float4 pnxt[4][2];

    // One step: uses buffer BU (holds B(v)), loads B(v+3) into BL.
    #define STEP(mm, aa, BU, BL) do {                                       \
        const int v_ = (mm) * 8 + (aa);                                     \
        if ((aa) == 6 && (mm) < 7) {                                        \
            _Pragma("unroll")                                               \
            for (int rt_ = 0; rt_ < 4; ++rt_) {                             \
                const int r_ = nblock * 64 + rt_ * 16 + cl;                 \
                const float* sr_ = sbuf + (size_t)r_ * EE + ((mm) + 1) * 32 \
                                 + koct * 8;                                \
                pnxt[rt_][0] = *(const float4*)(sr_);                       \
                pnxt[rt_][1] = *(const float4*)(sr_ + 4);                   \
            }                                                               \
        }                                                                   \
        f16x8 af_[4];                                                       \
        _Pragma("unroll")                                                   \
        for (int rt_ = 0; rt_ < 4; ++rt_) {                                 \
            const f16 xa_ = xf[rt_][(aa)];                                  \
            const f16x8 xa8_ = { xa_, xa_, xa_, xa_, xa_, xa_, xa_, xa_ };  \
            af_[rt_] = xa8_ * svm[rt_];                                     \
        }                                                                   \
        __builtin_amdgcn_s_setprio(1);                                      \
        _Pragma("unroll")                                                   \
        for (int ct_ = 0; ct_ < 4; ++ct_)                                   \
            _Pragma("unroll")                                               \
            for (int rt_ = 0; rt_ < 4; ++rt_)                               \
                acc[rt_][ct_] = __builtin_amdgcn_mfma_f32_16x16x32_f16(     \
                    af_[rt_], BU[ct_], acc[rt_][ct_], 0, 0, 0);             \
        __builtin_amdgcn_s_setprio(0);                                      \
        if (v_ + 3 < NSTEP) LOADB(BL, v_ + 3);                              \
        if ((aa) == 7 && (mm) < 7) {                                        \
            _Pragma("unroll")                                               \
            for (int rt_ = 0; rt_ < 4; ++rt_)                               \
                svm[rt_] = (f16x8){                                         \
                    (f16)pnxt[rt_][0].x, (f16)pnxt[rt_][0].y,               \
                    (f16)pnxt[rt_][0].z, (f16)pnxt[rt_][0].w,               \
                    (f16)pnxt[rt_][1].x, (f16)pnxt[rt_][1].y,               \
                    (f16)pnxt[rt_][1].z, (f16)pnxt[rt_][1].w };             \
        }                                                                   \
        __builtin_amdgcn_sched_barrier(0);                                  \
    } while (0)

    #pragma unroll
    for (int m = 0; m < 8; ++m) {
        STEP(m, 0, b0, b3);
        STEP(m, 1, b1, b0);
        STEP(m, 2, b2, b1);
        STEP(m, 3, b3, b2);
        STEP(m, 4, b0, b3);
        STEP(m, 5, b1, b0);
        STEP(m, 6, b2, b1);
        STEP(m, 7, b3, b2);
    }
    #undef STEP
    #undef LOADB
    #undef TOFF

    // ---- Epilogue: f16 via padded LDS stage, then contiguous row stores.
    __syncthreads();
    #pragma unroll
    for (int rt = 0; rt < 4; ++rt) {
        #pragma unroll
        for (int ct = 0; ct < 4; ++ct) {
            const int col = wave * 64 + ct * 16 + cl;
            #pragma unroll
            for (int q = 0; q < 4; ++q) {
                const int lr = rt * 16 + koct * 4 + q;
                Ep[lr * 264 + col] = (f16)acc[rt][ct][q];
            }
        }
    }
    __syncthreads();
    {
        const int lr  = tid >> 2;         // 0..63
        const int seg = tid & 3;          // 0..3 (64 cols each)
        f16* dst = part + ((size_t)chunk * NN + nblock * 64 + lr) * EE + seg * 64;
        const f16* srcE = Ep + lr * 264 + seg * 64;
        #pragma unroll
        for (int i = 0; i < 8; ++i)
            *(f16x8*)(dst + i * 8) = *(const f16x8*)(srcE + i * 8);
    }
}

// ---------------- Kernel 3: split-K reduce + residual + LayerNorm (f16 partials)
__global__ void reduce_ln_kernel(const float* __restrict__ x,
                                 const f16* __restrict__ part,
                                 const float* __restrict__ gamma,
                                 const float* __restrict__ beta,
                                 float* __restrict__ out) {
    const int n = blockIdx.x;
    const int c = threadIdx.x;
    const int lane = c & 63, wave = c >> 6;
    float y = x[(size_t)n * EE + c];
    #pragma unroll 8
    for (int ch = 0; ch < SPLITK; ++ch)
        y += (float)part[((size_t)ch * NN + n) * EE + c];

    float v = y;
    #pragma unroll
    for (int o = 32; o > 0; o >>= 1) v += __shfl_xor(v, o);
    __shared__ float red[8];
    if (lane == 0) red[wave] = v;
    __syncthreads();
    const float mean = (red[0] + red[1] + red[2] + red[3]) * (1.0f / EE);
    const float d = y - mean;
    float sq = d * d;
    #pragma unroll
    for (int o = 32; o > 0; o >>= 1) sq += __shfl_xor(sq, o);
    if (lane == 0) red[4 + wave] = sq;
    __syncthreads();
    const float var = (red[4] + red[5] + red[6] + red[7]) * (1.0f / EE);
    out[(size_t)n * EE + c] = d * rsqrtf(var + LN_EPS) * gamma[c] + beta[c];
}

extern "C" void kernel_launch(void* const* d_in, const int* in_sizes, int n_in,
                              void* d_out, int out_size, void* d_ws, size_t ws_size,
                              hipStream_t stream) {
    const float* x     = (const float*)d_in[0];
    const float* cm    = (const float*)d_in[1];
    const float* gamma = (const float*)d_in[2];
    const float* beta  = (const float*)d_in[3];
    float* out = (float*)d_out;

    float* sbuf = (float*)d_ws;                                    // 1 MB
    f16*   cmP  = (f16*)(sbuf + (size_t)NN * EE);                  // 33.5 MB
    f16*   part = (f16*)((char*)cmP + (size_t)TSTEPS * 8192 * sizeof(f16)); // 16.8 MB
    float* ps   = (float*)part;  // prefix partials (8.4 MB) alias part —
                                 // consumed by reduce_s before gemm writes part.

    hipLaunchKernelGGL(prep_kernel, dim3(NPACK + 144), dim3(256), 0, stream,
                       cm, cmP, x, ps);
    hipLaunchKernelGGL(reduce_s_kernel, dim3(NN), dim3(256), 0, stream, ps, sbuf);
    hipLaunchKernelGGL(gemm_kernel, dim3(16 * SPLITK), dim3(256), 0, stream,
                       x, sbuf, cmP, part);
    hipLaunchKernelGGL(reduce_ln_kernel, dim3(NN), dim3(256), 0, stream,
                       x, part, gamma, beta, out);
}